// Round 1
// baseline (177.326 us; speedup 1.0000x reference)
//
#include <hip/hip_runtime.h>

#define GP 60
#define GQ 40
#define NA 9
#define NELEM (GP * GQ * NA)   // 21600
#define KSEL 1000
#define MAXB 18
#define NTHREADS 256

// monotone map: ascending uint key <-> ascending float
__device__ __forceinline__ unsigned fkey(float f) {
  unsigned u = __float_as_uint(f);
  return (u & 0x80000000u) ? ~u : (u | 0x80000000u);
}

// Find bucket (from the TOP) containing the target-th largest element.
// hist[S] in LDS; part[256] scratch. Outputs: *outB = bucket, *outCum = count strictly above it.
__device__ void find_bucket(unsigned* hist, unsigned* part, int S, unsigned target,
                            unsigned* outB, unsigned* outCum) {
  const int tid = threadIdx.x;
  const int C = S >> 8;  // buckets per chunk of 256 chunks
  unsigned s = 0;
  for (int k = 0; k < C; ++k) s += hist[tid * C + k];
  part[tid] = s;
  __syncthreads();
  if (tid == 0) {
    unsigned cum = 0;
    int t = 255;
    for (; t > 0; --t) {
      if (cum + part[t] >= target) break;
      cum += part[t];
    }
    int bsel = t * C;
    for (int i = t * C + C - 1; i >= t * C; --i) {
      unsigned c = hist[i];
      if (cum + c >= target) { bsel = i; break; }
      cum += c;
    }
    *outB = (unsigned)bsel;
    *outCum = cum;
  }
  __syncthreads();
}

__global__ __launch_bounds__(NTHREADS) void rpn_kernel(
    const float* __restrict__ x, const float* __restrict__ anch,
    float* __restrict__ out) {
  const int b = blockIdx.x;
  const int tid = threadIdx.x;
  const float* xb = x + (size_t)b * NELEM * 6;

  __shared__ unsigned hist[2048];
  __shared__ unsigned part[256];
  __shared__ unsigned selKey[1024];
  __shared__ unsigned selIdx[1024];
  __shared__ float cX[KSEL], cY[KSEL], cW[KSEL], cH[KSEL], cS[KSEL];
  __shared__ float bX1[KSEL], bY1[KSEL], bX2[KSEL], bY2[KSEL], bAr[KSEL];
  __shared__ unsigned eqIdx[256];
  __shared__ unsigned sb1, sc1, sb2, sc2, sb3, sc3;
  __shared__ unsigned cntG, cntE;
  __shared__ int keptRank[MAXB];
  __shared__ int numKept;

  // ---- pass 1: histogram of top 11 bits ----
  for (int i = tid; i < 2048; i += NTHREADS) hist[i] = 0;
  __syncthreads();
  for (int i = tid; i < NELEM; i += NTHREADS)
    atomicAdd(&hist[fkey(xb[i * 6]) >> 21], 1u);
  __syncthreads();
  find_bucket(hist, part, 2048, KSEL, &sb1, &sc1);
  const unsigned b1 = sb1, G1 = sc1;

  // ---- pass 2: middle 11 bits within bucket b1 ----
  for (int i = tid; i < 2048; i += NTHREADS) hist[i] = 0;
  __syncthreads();
  for (int i = tid; i < NELEM; i += NTHREADS) {
    unsigned k = fkey(xb[i * 6]);
    if ((k >> 21) == b1) atomicAdd(&hist[(k >> 10) & 0x7FFu], 1u);
  }
  __syncthreads();
  find_bucket(hist, part, 2048, KSEL - G1, &sb2, &sc2);
  const unsigned b2 = sb2, G2 = G1 + sc2;

  // ---- pass 3: low 10 bits within (b1,b2) ----
  for (int i = tid; i < 1024; i += NTHREADS) hist[i] = 0;
  __syncthreads();
  const unsigned top22 = (b1 << 11) | b2;
  for (int i = tid; i < NELEM; i += NTHREADS) {
    unsigned k = fkey(xb[i * 6]);
    if ((k >> 10) == top22) atomicAdd(&hist[k & 0x3FFu], 1u);
  }
  __syncthreads();
  find_bucket(hist, part, 1024, KSEL - G2, &sb3, &sc3);
  const unsigned T = (b1 << 21) | (b2 << 10) | sb3;

  // ---- compaction: keys > T, plus smallest-index keys == T ----
  if (tid == 0) { cntG = 0; cntE = 0; }
  __syncthreads();
  for (int i = tid; i < NELEM; i += NTHREADS) {
    unsigned k = fkey(xb[i * 6]);
    if (k > T) {
      unsigned p = atomicAdd(&cntG, 1u);
      selKey[p] = k;
      selIdx[p] = (unsigned)i;
    } else if (k == T) {
      unsigned p = atomicAdd(&cntE, 1u);
      if (p < 256u) eqIdx[p] = (unsigned)i;
    }
  }
  __syncthreads();
  if (tid == 0) {
    const int G = (int)cntG;
    const int E = KSEL - G;                 // >= 1 by construction
    const int ne = (cntE < 256u) ? (int)cntE : 256;
    // insertion sort of equal-key indices (typically ne == 1)
    for (int a = 1; a < ne; ++a) {
      unsigned v = eqIdx[a];
      int j = a - 1;
      while (j >= 0 && eqIdx[j] > v) { eqIdx[j + 1] = eqIdx[j]; --j; }
      eqIdx[j + 1] = v;
    }
    for (int t = 0; t < E; ++t) {
      selKey[G + t] = T;
      selIdx[G + t] = (t < ne) ? eqIdx[t] : eqIdx[0];
    }
  }
  // pad to 1024 with minimal composites
  for (int i = tid + KSEL; i < 1024; i += NTHREADS) {
    selKey[i] = 0u;
    selIdx[i] = 0xFFFFFFFFu;
  }
  __syncthreads();

  // ---- bitonic sort 1024, descending by (key, then ascending idx) ----
  for (unsigned k = 2; k <= 1024; k <<= 1) {
    for (unsigned j = k >> 1; j > 0; j >>= 1) {
      __syncthreads();
      for (unsigned v = tid; v < 1024; v += NTHREADS) {
        unsigned l = v ^ j;
        if (l > v) {
          unsigned kv = selKey[v], kl = selKey[l];
          unsigned iv = selIdx[v], il = selIdx[l];
          bool less = (kv < kl) || (kv == kl && iv > il);
          bool greater = (kv > kl) || (kv == kl && iv < il);
          bool doswap = ((v & k) == 0) ? less : greater;
          if (doswap) {
            selKey[v] = kl; selKey[l] = kv;
            selIdx[v] = il; selIdx[l] = iv;
          }
        }
      }
    }
  }
  __syncthreads();

  // ---- decode 1000 candidates ----
  for (int r = tid; r < KSEL; r += NTHREADS) {
    unsigned idx = selIdx[r];
    const float* e = xb + idx * 6;
    float sc = e[0];
    float r0 = e[2], r1 = e[3], r2 = e[4], r3 = e[5];
    unsigned p = (idx / 9u) % 60u;
    unsigned q = idx / 540u;
    unsigned sr = idx % 9u;
    const float* ap = anch + (((p * 40u + q) * 9u + sr) * 4u);
    float ax = ap[0], ay = ap[1], aw = ap[2], ah = ap[3];
    float xc = r0 * aw + ax;
    float yc = r1 * ah + ay;
    float w = aw * expf(r2);
    float h = ah * expf(r3);
    float x1 = xc - 0.5f * w, x2 = xc + 0.5f * w;
    float y1 = yc - 0.5f * h, y2 = yc + 0.5f * h;
    cX[r] = xc; cY[r] = yc; cW[r] = w; cH[r] = h; cS[r] = sc;
    bX1[r] = x1; bY1[r] = y1; bX2[r] = x2; bY2[r] = y2;
    bAr[r] = (x2 - x1) * (y2 - y1);
  }
  __syncthreads();

  // ---- greedy NMS on wave 0, early exit at 18 kept ----
  if (tid < 64) {
    const int lane = tid;
    int nk = 0;
    float kx1 = 0.f, ky1 = 0.f, kx2 = 0.f, ky2 = 0.f;  // lane i holds kept box i
    int krank = -1;
    for (int base = 0; base < KSEL && nk < MAXB; base += 64) {
      int c = base + lane;
      bool alive = (c < KSEL);
      int cc = alive ? c : 0;
      float x1 = bX1[cc], y1 = bY1[cc], x2 = bX2[cc], y2 = bY2[cc], ar = bAr[cc];
      // pre-filter against existing kept boxes (all higher-scored)
      for (int i = 0; i < nk; ++i) {
        float px1 = __shfl(kx1, i), py1 = __shfl(ky1, i);
        float px2 = __shfl(kx2, i), py2 = __shfl(ky2, i);
        float iw = fmaxf(fminf(x2, px2) - fmaxf(x1, px1), 0.f);
        float ih = fmaxf(fminf(y2, py2) - fmaxf(y1, py1), 0.f);
        if (iw * ih / ar > 0.5f) alive = false;
      }
      unsigned long long m = __ballot(alive);
      // resolve survivors in score order
      while (m) {
        int i = __builtin_ctzll(m);      // lowest alive lane = best remaining score
        float px1 = __shfl(x1, i), py1 = __shfl(y1, i);
        float px2 = __shfl(x2, i), py2 = __shfl(y2, i);
        if (lane == nk) { kx1 = px1; ky1 = py1; kx2 = px2; ky2 = py2; krank = base + i; }
        ++nk;
        if (nk >= MAXB) break;
        if (alive && lane != i) {
          float iw = fmaxf(fminf(x2, px2) - fmaxf(x1, px1), 0.f);
          float ih = fmaxf(fminf(y2, py2) - fmaxf(y1, py1), 0.f);
          if (iw * ih / ar > 0.5f) alive = false;
        }
        if (lane == i) alive = false;
        m = __ballot(alive);
      }
    }
    if (lane == 0) numKept = nk;
    if (lane < nk) keptRank[lane] = krank;
  }
  __syncthreads();

  // ---- output: kept rows then pad rows cand[j - n] ----
  const int n = numKept;
  if (tid < MAXB * 5) {
    int j = tid / 5, c = tid % 5;
    int r = (j < n) ? keptRank[j] : (j - n);
    float v = (c == 0) ? cX[r] : (c == 1) ? cY[r] : (c == 2) ? cW[r]
             : (c == 3) ? cH[r] : cS[r];
    out[b * (MAXB * 5) + tid] = v;
  }
}

extern "C" void kernel_launch(void* const* d_in, const int* in_sizes, int n_in,
                              void* d_out, int out_size, void* d_ws, size_t ws_size,
                              hipStream_t stream) {
  const float* x = (const float*)d_in[0];
  const float* anch = (const float*)d_in[1];
  float* out = (float*)d_out;
  const int B = in_sizes[0] / (NELEM * 6);
  rpn_kernel<<<dim3(B), dim3(NTHREADS), 0, stream>>>(x, anch, out);
}

// Round 2
// 75.294 us; speedup vs baseline: 2.3551x; 2.3551x over previous
//
#include <hip/hip_runtime.h>

#define GP 60
#define GQ 40
#define NA 9
#define NELEM (GP * GQ * NA)   // 21600
#define KSEL 1000
#define MAXB 18
#define NT 1024
#define CAP 2048

// monotone map: ascending uint key <-> ascending float
__device__ __forceinline__ unsigned fkey(float f) {
  unsigned u = __float_as_uint(f);
  return (u & 0x80000000u) ? ~u : (u | 0x80000000u);
}

// All 1024 threads. hist[2048]. Picks bucket B with cntGe(B) >= target > cntGe(B+1).
// outCnt = cntGe(B), outAbove = cntGe(B+1). Parallel suffix scan, no serial section.
__device__ void select_bucket(unsigned* hist, unsigned* part, unsigned target,
                              unsigned* outB, unsigned* outCnt, unsigned* outAbove) {
  const int t = threadIdx.x;
  part[t] = hist[2 * t] + hist[2 * t + 1];
  __syncthreads();
  for (int s = 1; s < 1024; s <<= 1) {
    unsigned v = part[t] + ((t + s < 1024) ? part[t + s] : 0u);
    __syncthreads();
    part[t] = v;
    __syncthreads();
  }
  // part[t] = count(key >= bucket 2t)
  unsigned sufE = part[t];
  unsigned sufN = (t < 1023) ? part[t + 1] : 0u;
  unsigned geOdd = sufN + hist[2 * t + 1];
  if (sufE >= target && geOdd < target) { *outB = 2u * t;     *outCnt = sufE;  *outAbove = geOdd; }
  if (geOdd >= target && sufN < target) { *outB = 2u * t + 1; *outCnt = geOdd; *outAbove = sufN;  }
  __syncthreads();
}

__global__ __launch_bounds__(NT) void rpn_kernel(
    const float* __restrict__ x, const float* __restrict__ anch,
    float* __restrict__ out) {
  const int b = blockIdx.x;
  const int tid = threadIdx.x;
  const float* xb = x + (size_t)b * NELEM * 6;

  __shared__ unsigned hist[2048];
  __shared__ unsigned part[1024];
  __shared__ unsigned selKey[CAP];
  __shared__ unsigned selIdx[CAP];
  __shared__ float bX1[KSEL], bY1[KSEL], bX2[KSEL], bY2[KSEL], bAr[KSEL];
  __shared__ unsigned sB, sCnt, sAbove;
  __shared__ unsigned baseKey;
  __shared__ unsigned cnt;
  __shared__ int keptRank[MAXB];
  __shared__ int numKept;

  // ---- phase 1: histogram of top 11 key bits ----
  hist[2 * tid] = 0u; hist[2 * tid + 1] = 0u;
  __syncthreads();
  for (int i = tid; i < NELEM; i += NT)
    atomicAdd(&hist[fkey(xb[i * 6]) >> 21], 1u);
  __syncthreads();
  select_bucket(hist, part, KSEL, &sB, &sCnt, &sAbove);
  const unsigned b1 = sB, cnt1 = sCnt, above1 = sAbove;

  if (cnt1 <= CAP) {
    if (tid == 0) baseKey = b1 << 21;
  } else {
    // rare fat-bucket: refine within bucket b1 on next 11 bits
    hist[2 * tid] = 0u; hist[2 * tid + 1] = 0u;
    __syncthreads();
    for (int i = tid; i < NELEM; i += NT) {
      unsigned k = fkey(xb[i * 6]);
      if ((k >> 21) == b1) atomicAdd(&hist[(k >> 10) & 0x7FFu], 1u);
    }
    __syncthreads();
    select_bucket(hist, part, KSEL - above1, &sB, &sCnt, &sAbove);
    if (tid == 0) baseKey = (b1 << 21) | (sB << 10);
  }
  if (tid == 0) cnt = 0u;
  __syncthreads();

  // ---- compact: all keys >= baseKey (count in (1000, 2048] by construction) ----
  const unsigned TB = baseKey;
  for (int i = tid; i < NELEM; i += NT) {
    unsigned k = fkey(xb[i * 6]);
    if (k >= TB) {
      unsigned p = atomicAdd(&cnt, 1u);
      if (p < CAP) { selKey[p] = k; selIdx[p] = (unsigned)i; }
    }
  }
  __syncthreads();
  const unsigned realCnt = (cnt < CAP) ? cnt : CAP;
  for (unsigned i = realCnt + tid; i < CAP; i += NT) {
    selKey[i] = 0u;
    selIdx[i] = 0xFFFFFFFFu;
  }
  __syncthreads();

  // ---- bitonic sort 2048 desc by (key, then ascending idx); 1 pair per thread ----
  for (unsigned k = 2; k <= CAP; k <<= 1) {
    for (unsigned j = k >> 1; j > 0; j >>= 1) {
      unsigned p = (unsigned)tid;
      unsigned v = ((p & ~(j - 1)) << 1) | (p & (j - 1));
      unsigned l = v | j;
      unsigned kv = selKey[v], kl = selKey[l];
      unsigned iv = selIdx[v], il = selIdx[l];
      bool less    = (kv < kl) || (kv == kl && iv > il);
      bool greater = (kv > kl) || (kv == kl && iv < il);
      bool doswap = ((v & k) == 0) ? less : greater;
      if (doswap) {
        selKey[v] = kl; selKey[l] = kv;
        selIdx[v] = il; selIdx[l] = iv;
      }
      __syncthreads();
    }
  }

  // ---- decode first 1000 into box arrays for NMS ----
  if (tid < KSEL) {
    unsigned idx = selIdx[tid];
    const float* e = xb + idx * 6;
    float r0 = e[2], r1 = e[3], r2 = e[4], r3 = e[5];
    unsigned pp = (idx / 9u) % 60u;
    unsigned qq = idx / 540u;
    unsigned sr = idx % 9u;
    const float* ap = anch + (((pp * 40u + qq) * 9u + sr) * 4u);
    float ax = ap[0], ay = ap[1], aw = ap[2], ah = ap[3];
    float xc = r0 * aw + ax;
    float yc = r1 * ah + ay;
    float w = aw * expf(r2);
    float h = ah * expf(r3);
    float x1 = xc - 0.5f * w, x2 = xc + 0.5f * w;
    float y1 = yc - 0.5f * h, y2 = yc + 0.5f * h;
    bX1[tid] = x1; bY1[tid] = y1; bX2[tid] = x2; bY2[tid] = y2;
    bAr[tid] = (x2 - x1) * (y2 - y1);
  }
  __syncthreads();

  // ---- greedy NMS on wave 0, early exit at 18 kept ----
  if (tid < 64) {
    const int lane = tid;
    int nk = 0;
    float kx1 = 0.f, ky1 = 0.f, kx2 = 0.f, ky2 = 0.f;  // lane i holds kept box i
    int krank = -1;
    for (int base = 0; base < KSEL && nk < MAXB; base += 64) {
      int c = base + lane;
      bool alive = (c < KSEL);
      int cc = alive ? c : 0;
      float x1 = bX1[cc], y1 = bY1[cc], x2 = bX2[cc], y2 = bY2[cc], ar = bAr[cc];
      for (int i = 0; i < nk; ++i) {
        float px1 = __shfl(kx1, i), py1 = __shfl(ky1, i);
        float px2 = __shfl(kx2, i), py2 = __shfl(ky2, i);
        float iw = fmaxf(fminf(x2, px2) - fmaxf(x1, px1), 0.f);
        float ih = fmaxf(fminf(y2, py2) - fmaxf(y1, py1), 0.f);
        if (iw * ih / ar > 0.5f) alive = false;
      }
      unsigned long long m = __ballot(alive);
      while (m) {
        int i = __builtin_ctzll(m);      // lowest alive lane = best remaining score
        float px1 = __shfl(x1, i), py1 = __shfl(y1, i);
        float px2 = __shfl(x2, i), py2 = __shfl(y2, i);
        if (lane == nk) { kx1 = px1; ky1 = py1; kx2 = px2; ky2 = py2; krank = base + i; }
        ++nk;
        if (nk >= MAXB) break;
        if (alive && lane != i) {
          float iw = fmaxf(fminf(x2, px2) - fmaxf(x1, px1), 0.f);
          float ih = fmaxf(fminf(y2, py2) - fmaxf(y1, py1), 0.f);
          if (iw * ih / ar > 0.5f) alive = false;
        }
        if (lane == i) alive = false;
        m = __ballot(alive);
      }
    }
    if (lane == 0) numKept = nk;
    if (lane < nk) keptRank[lane] = krank;
  }
  __syncthreads();

  // ---- output: kept rows then pad rows cand[j - n]; re-decode from selIdx ----
  const int n = numKept;
  if (tid < MAXB) {
    int j = tid;
    int r = (j < n) ? keptRank[j] : (j - n);
    unsigned idx = selIdx[r];
    const float* e = xb + idx * 6;
    float sc = e[0];
    float r0 = e[2], r1 = e[3], r2 = e[4], r3 = e[5];
    unsigned pp = (idx / 9u) % 60u;
    unsigned qq = idx / 540u;
    unsigned sr = idx % 9u;
    const float* ap = anch + (((pp * 40u + qq) * 9u + sr) * 4u);
    float ax = ap[0], ay = ap[1], aw = ap[2], ah = ap[3];
    float xc = r0 * aw + ax;
    float yc = r1 * ah + ay;
    float w = aw * expf(r2);
    float h = ah * expf(r3);
    float* o = out + b * (MAXB * 5) + j * 5;
    o[0] = xc; o[1] = yc; o[2] = w; o[3] = h; o[4] = sc;
  }
}

extern "C" void kernel_launch(void* const* d_in, const int* in_sizes, int n_in,
                              void* d_out, int out_size, void* d_ws, size_t ws_size,
                              hipStream_t stream) {
  const float* x = (const float*)d_in[0];
  const float* anch = (const float*)d_in[1];
  float* out = (float*)d_out;
  const int B = in_sizes[0] / (NELEM * 6);
  rpn_kernel<<<dim3(B), dim3(NT), 0, stream>>>(x, anch, out);
}

// Round 3
// 66.867 us; speedup vs baseline: 2.6519x; 1.1260x over previous
//
#include <hip/hip_runtime.h>

#define GP 60
#define GQ 40
#define NA 9
#define NELEM (GP * GQ * NA)   // 21600
#define KSEL 1000
#define MAXB 18
#define NT 1024
#define CAP 2048
#define NFULL 21              // 21*1024 = 21504 full iterations
#define NTAIL (NELEM - NFULL * NT)  // 96

typedef unsigned long long ull;

// monotone map: ascending uint key <-> ascending float
__device__ __forceinline__ unsigned fkey(float f) {
  unsigned u = __float_as_uint(f);
  return (u & 0x80000000u) ? ~u : (u | 0x80000000u);
}

// Wave-shuffle bucket select over hist[2048]. 16 waves x 128 buckets.
// Picks bucket B with cntGe(B) >= target > cntGe(B+1).
__device__ void select_bucket(const unsigned* hist, unsigned target,
                              volatile unsigned* chunkSuf,  // [16] scratch
                              unsigned* outB, unsigned* outCnt, unsigned* outAbove) {
  const int tid = threadIdx.x;
  const int w = tid >> 6, l = tid & 63;
  unsigned h1 = hist[w * 128 + 2 * l + 1];
  unsigned s = hist[w * 128 + 2 * l] + h1;
  // inclusive suffix scan of pair-sums within wave
  #pragma unroll
  for (int d = 1; d < 64; d <<= 1) {
    unsigned t = __shfl_down(s, d);
    if (l + d < 64) s += t;
  }
  if (l == 0) chunkSuf[w] = s;
  __syncthreads();
  if (w == 0) {
    unsigned ct = (l < 16) ? chunkSuf[l] : 0u;
    unsigned cs = ct;
    #pragma unroll
    for (int d = 1; d < 16; d <<= 1) {
      unsigned t = __shfl_down(cs, d);
      if (l + d < 16) cs += t;
    }
    if (l < 16) chunkSuf[l] = cs - ct;   // count in chunks strictly after l
  }
  __syncthreads();
  unsigned base = chunkSuf[w];
  unsigned sufE = s + base;                        // cntGe(bucket w*128+2l)
  unsigned sN = __shfl_down(s, 1);
  unsigned sufN = ((l < 63) ? sN : 0u) + base;     // cntGe(bucket w*128+2l+2)
  unsigned geOdd = sufN + h1;                      // cntGe(bucket w*128+2l+1)
  if (sufE >= target && geOdd < target) { *outB = w * 128u + 2u * l;     *outCnt = sufE;  *outAbove = geOdd; }
  if (geOdd >= target && sufN < target) { *outB = w * 128u + 2u * l + 1; *outCnt = geOdd; *outAbove = sufN;  }
  __syncthreads();
}

__global__ __launch_bounds__(NT) void rpn_kernel(
    const float* __restrict__ x, const float* __restrict__ anch,
    float* __restrict__ out) {
  const int b = blockIdx.x;
  const int tid = threadIdx.x;
  const float* xb = x + (size_t)b * NELEM * 6;

  __shared__ unsigned hist[2048];
  __shared__ unsigned chunkSuf[16];
  __shared__ ull selPk[CAP];
  __shared__ float bX1[KSEL], bY1[KSEL], bX2[KSEL], bY2[KSEL], bAr[KSEL];
  __shared__ unsigned sB, sCnt, sAbove;
  __shared__ unsigned baseKey;
  __shared__ unsigned cnt;
  __shared__ int keptRank[MAXB];
  __shared__ int numKept;

  // ---- scan 1: deep-prefetch scores, histogram top 11 key bits ----
  float v[NFULL];
  #pragma unroll
  for (int u = 0; u < NFULL; ++u)
    v[u] = xb[(size_t)(tid + (u << 10)) * 6];
  float vtail = 0.f;
  const bool hastail = tid < NTAIL;
  if (hastail) vtail = xb[(size_t)(tid + NFULL * NT) * 6];

  hist[2 * tid >= 2048 ? 0 : 2 * tid] = 0u;  // placate compiler; real init below
  hist[2 * tid] = 0u; hist[2 * tid + 1] = 0u;
  __syncthreads();
  #pragma unroll
  for (int u = 0; u < NFULL; ++u)
    atomicAdd(&hist[fkey(v[u]) >> 21], 1u);
  if (hastail) atomicAdd(&hist[fkey(vtail) >> 21], 1u);
  __syncthreads();
  select_bucket(hist, KSEL, chunkSuf, &sB, &sCnt, &sAbove);
  const unsigned b1 = sB, cnt1 = sCnt, above1 = sAbove;

  if (cnt1 <= CAP) {
    if (tid == 0) baseKey = b1 << 21;
  } else {
    // rare fat-bucket: refine within bucket b1 on next 11 bits (slow path ok)
    hist[2 * tid] = 0u; hist[2 * tid + 1] = 0u;
    __syncthreads();
    #pragma unroll
    for (int u = 0; u < NFULL; ++u) {
      unsigned k = fkey(v[u]);
      if ((k >> 21) == b1) atomicAdd(&hist[(k >> 10) & 0x7FFu], 1u);
    }
    if (hastail) {
      unsigned k = fkey(vtail);
      if ((k >> 21) == b1) atomicAdd(&hist[(k >> 10) & 0x7FFu], 1u);
    }
    __syncthreads();
    select_bucket(hist, KSEL - above1, chunkSuf, &sB, &sCnt, &sAbove);
    if (tid == 0) baseKey = (b1 << 21) | (sB << 10);
  }
  if (tid == 0) cnt = 0u;
  __syncthreads();

  // ---- compact from registers: keys >= baseKey, packed (key,~idx) ----
  const unsigned TB = baseKey;
  #pragma unroll
  for (int u = 0; u < NFULL; ++u) {
    unsigned k = fkey(v[u]);
    if (k >= TB) {
      unsigned p = atomicAdd(&cnt, 1u);
      unsigned i = (unsigned)(tid + (u << 10));
      if (p < CAP) selPk[p] = ((ull)k << 32) | (unsigned)(~i);
    }
  }
  if (hastail) {
    unsigned k = fkey(vtail);
    if (k >= TB) {
      unsigned p = atomicAdd(&cnt, 1u);
      unsigned i = (unsigned)(tid + NFULL * NT);
      if (p < CAP) selPk[p] = ((ull)k << 32) | (unsigned)(~i);
    }
  }
  __syncthreads();
  const unsigned realCnt = (cnt < CAP) ? cnt : CAP;
  for (unsigned i = realCnt + tid; i < CAP; i += NT) selPk[i] = 0ull;
  __syncthreads();

  // ---- bitonic sort 2048 descending by packed key; 1 pair per thread ----
  for (unsigned k = 2; k <= CAP; k <<= 1) {
    for (unsigned j = k >> 1; j > 0; j >>= 1) {
      unsigned p = (unsigned)tid;
      unsigned vi = ((p & ~(j - 1)) << 1) | (p & (j - 1));
      unsigned li = vi | j;
      ull a = selPk[vi], c = selPk[li];
      bool doswap = ((vi & k) == 0) ? (a < c) : (a > c);
      if (doswap) { selPk[vi] = c; selPk[li] = a; }
      __syncthreads();
    }
  }

  // ---- decode first 1000 into box arrays for NMS ----
  if (tid < KSEL) {
    unsigned idx = ~(unsigned)selPk[tid];
    const float* e = xb + (size_t)idx * 6;
    float r0 = e[2], r1 = e[3], r2 = e[4], r3 = e[5];
    unsigned pp = (idx / 9u) % 60u;
    unsigned qq = idx / 540u;
    unsigned sr = idx % 9u;
    const float* ap = anch + (((pp * 40u + qq) * 9u + sr) * 4u);
    float ax = ap[0], ay = ap[1], aw = ap[2], ah = ap[3];
    float xc = r0 * aw + ax;
    float yc = r1 * ah + ay;
    float w = aw * expf(r2);
    float h = ah * expf(r3);
    float x1 = xc - 0.5f * w, x2 = xc + 0.5f * w;
    float y1 = yc - 0.5f * h, y2 = yc + 0.5f * h;
    bX1[tid] = x1; bY1[tid] = y1; bX2[tid] = x2; bY2[tid] = y2;
    bAr[tid] = (x2 - x1) * (y2 - y1);
  }
  __syncthreads();

  // ---- greedy NMS on wave 0, early exit at 18 kept ----
  if (tid < 64) {
    const int lane = tid;
    int nk = 0;
    float kx1 = 0.f, ky1 = 0.f, kx2 = 0.f, ky2 = 0.f;  // lane i holds kept box i
    int krank = -1;
    for (int base = 0; base < KSEL && nk < MAXB; base += 64) {
      int c = base + lane;
      bool alive = (c < KSEL);
      int cc = alive ? c : 0;
      float x1 = bX1[cc], y1 = bY1[cc], x2 = bX2[cc], y2 = bY2[cc], ar = bAr[cc];
      for (int i = 0; i < nk; ++i) {
        float px1 = __shfl(kx1, i), py1 = __shfl(ky1, i);
        float px2 = __shfl(kx2, i), py2 = __shfl(ky2, i);
        float iw = fmaxf(fminf(x2, px2) - fmaxf(x1, px1), 0.f);
        float ih = fmaxf(fminf(y2, py2) - fmaxf(y1, py1), 0.f);
        if (iw * ih / ar > 0.5f) alive = false;
      }
      unsigned long long m = __ballot(alive);
      while (m) {
        int i = __builtin_ctzll(m);      // lowest alive lane = best remaining score
        float px1 = __shfl(x1, i), py1 = __shfl(y1, i);
        float px2 = __shfl(x2, i), py2 = __shfl(y2, i);
        if (lane == nk) { kx1 = px1; ky1 = py1; kx2 = px2; ky2 = py2; krank = base + i; }
        ++nk;
        if (nk >= MAXB) break;
        if (alive && lane != i) {
          float iw = fmaxf(fminf(x2, px2) - fmaxf(x1, px1), 0.f);
          float ih = fmaxf(fminf(y2, py2) - fmaxf(y1, py1), 0.f);
          if (iw * ih / ar > 0.5f) alive = false;
        }
        if (lane == i) alive = false;
        m = __ballot(alive);
      }
    }
    if (lane == 0) numKept = nk;
    if (lane < nk) keptRank[lane] = krank;
  }
  __syncthreads();

  // ---- output: kept rows then pad rows cand[j - n]; re-decode ----
  const int n = numKept;
  if (tid < MAXB) {
    int j = tid;
    int r = (j < n) ? keptRank[j] : (j - n);
    unsigned idx = ~(unsigned)selPk[r];
    const float* e = xb + (size_t)idx * 6;
    float sc = e[0];
    float r0 = e[2], r1 = e[3], r2 = e[4], r3 = e[5];
    unsigned pp = (idx / 9u) % 60u;
    unsigned qq = idx / 540u;
    unsigned sr = idx % 9u;
    const float* ap = anch + (((pp * 40u + qq) * 9u + sr) * 4u);
    float ax = ap[0], ay = ap[1], aw = ap[2], ah = ap[3];
    float xc = r0 * aw + ax;
    float yc = r1 * ah + ay;
    float w = aw * expf(r2);
    float h = ah * expf(r3);
    float* o = out + b * (MAXB * 5) + j * 5;
    o[0] = xc; o[1] = yc; o[2] = w; o[3] = h; o[4] = sc;
  }
}

extern "C" void kernel_launch(void* const* d_in, const int* in_sizes, int n_in,
                              void* d_out, int out_size, void* d_ws, size_t ws_size,
                              hipStream_t stream) {
  const float* x = (const float*)d_in[0];
  const float* anch = (const float*)d_in[1];
  float* out = (float*)d_out;
  const int B = in_sizes[0] / (NELEM * 6);
  rpn_kernel<<<dim3(B), dim3(NT), 0, stream>>>(x, anch, out);
}